// Round 9
// baseline (87.430 us; speedup 1.0000x reference)
//
#include <hip/hip_runtime.h>
#include <hip/hip_bf16.h>

#define NL  128   // layers (n)
#define DK  256   // d_in (k)
#define DO_ 256   // d_out (o)
#define MB  1024  // batch (m)

typedef __attribute__((ext_vector_type(4))) float f32x4;
typedef __attribute__((ext_vector_type(8))) short bf16x8;
typedef __attribute__((ext_vector_type(8))) unsigned short u16x8;
typedef __attribute__((ext_vector_type(4))) unsigned short u16x4;

static __device__ __forceinline__ unsigned short f2bf(float f) {
  __hip_bfloat16 h = __float2bfloat16(f);
  return __builtin_bit_cast(unsigned short, h);
}

// ---------------------------------------------------------------------------
// Prep: W[n][k][o] fp32 -> Wt in MFMA B-fragment order, bf16 (verified R4-R8):
//   unit (o, kc[8-k chunk]) -> ob=o>>4, lrow=o&15, s=kc>>2, lhi=kc&3
//   elem offset = ((n*16+ob)*8 + s)*512 + (lhi*16+lrow)*8 + (k&7)
// so a wave's B-load for (ob, s) is ONE contiguous 1KB dwordx4 per lane.
// ---------------------------------------------------------------------------
__global__ __launch_bounds__(256) void wt_prep(const float* __restrict__ W,
                                               unsigned short* __restrict__ Wt) {
  const int n     = blockIdx.y;
  const int ktile = (blockIdx.x >> 2) * 64;
  const int otile = (blockIdx.x & 3) * 64;
  __shared__ float tile[64][65];  // +1 pad: conflict-free column reads
  const float* Wn = W + (size_t)n * DK * DO_;
  const int t  = threadIdx.x;
  const int lr = t >> 4;
  const int lc = (t & 15) * 4;
#pragma unroll
  for (int p = 0; p < 4; ++p) {
    const int k = p * 16 + lr;
    const float4 v = *(const float4*)(Wn + (size_t)(ktile + k) * DO_ + otile + lc);
    tile[k][lc + 0] = v.x; tile[k][lc + 1] = v.y;
    tile[k][lc + 2] = v.z; tile[k][lc + 3] = v.w;
  }
  __syncthreads();
  const int ol = t >> 2;            // local o 0..63
  const int o  = otile + ol;
  const int kq = t & 3;
  unsigned short* Wt_n = Wt + (size_t)n * DO_ * DK;
#pragma unroll
  for (int h = 0; h < 2; ++h) {
    u16x8 w;
#pragma unroll
    for (int j = 0; j < 8; ++j) w[j] = f2bf(tile[kq * 16 + h * 8 + j][ol]);
    const int kc = (ktile >> 3) + kq * 2 + h;   // global 8-k chunk id (0..31)
    const int ob = o >> 4, lrw = o & 15, s = kc >> 2, lh = kc & 3;
    *(u16x8*)(Wt_n + ((size_t)(ob * 8 + s) * 64 + lh * 16 + lrw) * 8) = w;
  }
}

// ---------------------------------------------------------------------------
// Main: R8 + sustained-issue 2-group pipeline. Block = (n, m-groups 2q,2q+1),
// 512 thr. Per group: convert g (vmcnt waits only g's loads) -> issue g+1's
// 8x1KB coalesced loads -> lgkmcnt(0)+RAW s_barrier (g+1 loads & g-1 stores
// stay in flight!) -> compute g (2-deep B prefetch, 64 MFMA/wave) -> stores
// -> bare s_barrier (WAR only). HBM loads/stores are outstanding through
// ~80% of wave lifetime instead of ~20%.
// XCD swizzle: bid&7 -> n in [xcd*16,+16): 2MB Wt slice per XCD L2.
// ---------------------------------------------------------------------------
__global__ __launch_bounds__(512, 4) void nlinear_mfma(
    const float* __restrict__ X, const unsigned short* __restrict__ Wt,
    const float* __restrict__ bias, float* __restrict__ out) {
  const int wid  = blockIdx.x;
  const int n    = (wid & 7) * 16 + ((wid >> 3) & 15);
  const int mgq  = wid >> 7;          // 0..7 -> m-groups 2q, 2q+1 (64 rows each)
  const int t    = threadIdx.x;
  const int wave = t >> 6;            // 0..7 = o-slice of 32
  const int lane = t & 63;
  const int lrow = lane & 15;
  const int lhi  = lane >> 4;

  __shared__ unsigned short Alds[64 * 256];  // 32 KB, 512B rows, swizzled slots

  const unsigned short* Wn = Wt + (size_t)n * DO_ * DK;

  // bias: load once, reused for both groups
  const float* bb = bias + n * DO_ + wave * 32 + lhi * 4;
  f32x4 bv[2];
#pragma unroll
  for (int oj = 0; oj < 2; ++oj) bv[oj] = *(const f32x4*)(bb + oj * 16);

  // ---- stage pointers: wave w stages rows w*8+j, lane takes k=lane*4 ----
  const float* xw = X + ((size_t)(mgq * 128 + wave * 8) * NL + n) * DK + lane * 4;

  // prologue: issue group-0 loads
  f32x4 xv[8];
#pragma unroll
  for (int j = 0; j < 8; ++j)
    xv[j] = *(const f32x4*)(xw + (size_t)j * NL * DK);

  char* ab = (char*)Alds;

#pragma unroll
  for (int g = 0; g < 2; ++g) {
    const int mbase = mgq * 128 + g * 64;

    // convert + write LDS (compiler waits vmcnt only for this group's xv)
#pragma unroll
    for (int j = 0; j < 8; ++j) {
      u16x4 h;
#pragma unroll
      for (int e = 0; e < 4; ++e) h[e] = f2bf(xv[j][e]);
      // row = wave*8+j; chunk c = lane>>1; slot = c ^ j  (verified R5-R8)
      *(u16x4*)(ab + (wave * 8 + j) * 512 + (((lane >> 1) ^ j) << 4) + (lane & 1) * 8) = h;
    }
    // issue NEXT group's loads now — in flight across this group's compute
    if (g == 0) {
#pragma unroll
      for (int j = 0; j < 8; ++j)
        xv[j] = *(const f32x4*)(xw + (size_t)(64 + j) * NL * DK);
    }
    // RAW barrier: LDS writes visible; does NOT drain vmcnt (loads/stores fly on)
    asm volatile("s_waitcnt lgkmcnt(0)" ::: "memory");
    __builtin_amdgcn_s_barrier();

    f32x4 acc[4][2];
#pragma unroll
    for (int mt = 0; mt < 4; ++mt)
#pragma unroll
      for (int oj = 0; oj < 2; ++oj) acc[mt][oj] = (f32x4){0.f, 0.f, 0.f, 0.f};

    // B-load: coalesced 1KB per instr from prefragmented, L2-resident Wt
#define BLOAD(s, oj) \
  (*(const bf16x8*)(Wn + ((size_t)(((wave * 2 + (oj)) * 8) + (s)) * 64 + lane) * 8))

    bf16x8 bA0 = BLOAD(0, 0), bA1 = BLOAD(0, 1);
    bf16x8 bB0 = BLOAD(1, 0), bB1 = BLOAD(1, 1);

#pragma unroll
    for (int s = 0; s < 8; ++s) {
      const bf16x8 bc0 = (s & 1) ? bB0 : bA0;
      const bf16x8 bc1 = (s & 1) ? bB1 : bA1;
      if (s < 6) {  // refill the slot just consumed with s+2
        if (s & 1) { bB0 = BLOAD(s + 2, 0); bB1 = BLOAD(s + 2, 1); }
        else       { bA0 = BLOAD(s + 2, 0); bA1 = BLOAD(s + 2, 1); }
      }
      bf16x8 af[4];
#pragma unroll
      for (int mt = 0; mt < 4; ++mt) {
        const int row = mt * 16 + lrow;
        af[mt] = *(const bf16x8*)(ab + row * 512 + (((s * 4 + lhi) ^ (row & 7)) << 4));
      }
#pragma unroll
      for (int mt = 0; mt < 4; ++mt) {  // SWAPPED: D[o][m], lane regs = 4 contig o
        acc[mt][0] = __builtin_amdgcn_mfma_f32_16x16x32_bf16(bc0, af[mt], acc[mt][0], 0, 0, 0);
        acc[mt][1] = __builtin_amdgcn_mfma_f32_16x16x32_bf16(bc1, af[mt], acc[mt][1], 0, 0, 0);
      }
    }
#undef BLOAD

    // epilogue: m = mbase + mt*16 + lrow, o = wave*32 + oj*16 + lhi*4 + r
#pragma unroll
    for (int mt = 0; mt < 4; ++mt) {
      const int m = mbase + mt * 16 + lrow;
      float* orow = out + ((size_t)m * NL + n) * DO_ + wave * 32 + lhi * 4;
#pragma unroll
      for (int oj = 0; oj < 2; ++oj)
        *(f32x4*)(orow + oj * 16) = acc[mt][oj] + bv[oj];
    }

    // WAR-only barrier before group 1 overwrites LDS: every wave's ds_reads
    // were consumed (lgkm waited) before its MFMAs, so a bare s_barrier
    // suffices — global stores and group-1 loads remain in flight.
    if (g == 0) __builtin_amdgcn_s_barrier();
  }
}

// ---------------------------------------------------------------------------
// Fallback (only if ws too small for Wt): plain fp32, correct but slow.
// ---------------------------------------------------------------------------
__global__ __launch_bounds__(256) void nlinear_naive(
    const float* __restrict__ X, const float* __restrict__ W,
    const float* __restrict__ B, float* __restrict__ out) {
  const int n = blockIdx.y;
  const int m = blockIdx.x;
  const int o = threadIdx.x;
  __shared__ float xs[DK];
  xs[o] = X[((size_t)m * NL + n) * DK + o];
  __syncthreads();
  const float* Wn = W + (size_t)n * DK * DO_;
  float s = B[n * DO_ + o];
  for (int k = 0; k < DK; ++k) s = fmaf(xs[k], Wn[(size_t)k * DO_ + o], s);
  out[((size_t)m * NL + n) * DO_ + o] = s;
}

extern "C" void kernel_launch(void* const* d_in, const int* in_sizes, int n_in,
                              void* d_out, int out_size, void* d_ws, size_t ws_size,
                              hipStream_t stream) {
  const float* x = (const float*)d_in[0];
  const float* w = (const float*)d_in[1];
  const float* b = (const float*)d_in[2];
  float* out     = (float*)d_out;
  const size_t wt_bytes = (size_t)NL * DK * DO_ * sizeof(unsigned short);
  if (ws_size >= wt_bytes) {
    unsigned short* wt = (unsigned short*)d_ws;
    wt_prep<<<dim3(16, NL), 256, 0, stream>>>(w, wt);
    nlinear_mfma<<<dim3(1024), 512, 0, stream>>>(x, wt, b, out);
  } else {
    nlinear_naive<<<dim3(MB, NL), 256, 0, stream>>>(x, w, b, out);
  }
}